// Round 5
// baseline (532.966 us; speedup 1.0000x reference)
//
#include <hip/hip_runtime.h>
#include <hip/hip_cooperative_groups.h>
#include <math.h>

namespace cg = cooperative_groups;

// Problem constants
#define NB 16
#define NL 128
#define DIN 512
#define NH 256
#define NTAGS 45
#define NM (NB*NL)          // 2048 rows
#define NJ (NL+1)           // 129 arc columns
#define NJP 132             // padded score row stride

// ws layout (floats)
#define HID_OFF   0
#define U_OFF     (NM*NH)                 // 524288
#define HV_OFF    (U_OFF + NM*NH)         // 1048576
#define VROOT_OFF (HV_OFF + NM*NH)        // 1572864
#define ACC_OFF   (VROOT_OFF + NH)        // 1573120
#define SC_OFF    (ACC_OFF + 4)           // scores: 2 x NM x NJP

#define NBLK 512

// Single cooperative kernel: all phases, grid.sync() between.
// 512 blocks x 256 thr = exactly 2 blocks/CU; LDS 17.9KB -> co-residency safe.
__global__ __launch_bounds__(256, 2) void fused_all(
    const float* __restrict__ ctx, const int* __restrict__ slens,
    const int* __restrict__ arcs, const int* __restrict__ labels,
    const float* __restrict__ W1, const float* __restrict__ b1,
    const float* __restrict__ root, const float* __restrict__ Wp,
    const float* __restrict__ bp, const float* __restrict__ W_arc,
    const float* __restrict__ W_lab, const float* __restrict__ b_lab,
    float* __restrict__ hidden, float* __restrict__ u, float* __restrict__ hv,
    float* __restrict__ vroot, float* __restrict__ accum,
    float* __restrict__ scores, float* __restrict__ out)
{
    cg::grid_group grid = cg::this_grid();
    __shared__ float smem[4480];          // union across phases (17.9 KB)
    int blk = blockIdx.x;
    int tid = threadIdx.x;

    //========== P1: hidden = relu(ctx@W1+b1), 256 tile-tasks; vroot 4 tasks ==
    if (blk == 0 && tid == 0) accum[0] = 0.f;
    if (blk < 256) {
        float (*As)[34] = (float(*)[34])smem;            // 544
        float (*Bs)[68] = (float(*)[68])(smem + 544);    // 1088
        int m0 = (blk >> 2) * 32;
        int n0 = (blk & 3) * 64;
        int tm = tid >> 4, tn = tid & 15;
        int lm = tid >> 2, lk = (tid & 3) * 4;
        int bk = tid >> 4, bn = (tid & 15) * 4;
        float acc[2][4] = {{0.f}};
        for (int k0 = 0; k0 < DIN; k0 += 16) {
            if (tid < 128) {
                float4 a4 = *(const float4*)&ctx[(m0 + lm) * DIN + k0 + lk];
                As[lk + 0][lm] = a4.x; As[lk + 1][lm] = a4.y;
                As[lk + 2][lm] = a4.z; As[lk + 3][lm] = a4.w;
            }
            float4 b4 = *(const float4*)&W1[(k0 + bk) * NH + n0 + bn];
            *(float4*)&Bs[bk][bn] = b4;
            __syncthreads();
            #pragma unroll
            for (int kk = 0; kk < 16; kk++) {
                float2 a2 = *(const float2*)&As[kk][tm * 2];
                float4 bv = *(const float4*)&Bs[kk][tn * 4];
                float ar[2] = {a2.x, a2.y};
                float br[4] = {bv.x, bv.y, bv.z, bv.w};
                #pragma unroll
                for (int r = 0; r < 2; r++)
                    #pragma unroll
                    for (int c = 0; c < 4; c++)
                        acc[r][c] += ar[r] * br[c];
            }
            __syncthreads();
        }
        int col = n0 + tn * 4;
        float4 bb = *(const float4*)&b1[col];
        #pragma unroll
        for (int r = 0; r < 2; r++) {
            int row = m0 + tm * 2 + r;
            float4 o;
            o.x = fmaxf(acc[r][0] + bb.x, 0.f);
            o.y = fmaxf(acc[r][1] + bb.y, 0.f);
            o.z = fmaxf(acc[r][2] + bb.z, 0.f);
            o.w = fmaxf(acc[r][3] + bb.w, 0.f);
            *(float4*)&hidden[row * NH + col] = o;
        }
    } else if (blk < 260) {
        // vroot cols q*64..q*64+63: thread = (kchunk, col), LDS reduce x4
        int q = blk - 256;
        int col = q * 64 + (tid & 63);
        int kc = tid >> 6;
        float p = 0.f;
        #pragma unroll 8
        for (int c = kc * 64; c < kc * 64 + 64; c++)
            p += root[c] * Wp[(NH + c) * NH + col];
        smem[kc * 64 + (tid & 63)] = p;
        __syncthreads();
        if (tid < 64)
            vroot[q * 64 + tid] = smem[tid] + smem[64 + tid]
                                + smem[128 + tid] + smem[192 + tid];
    }
    __threadfence();
    grid.sync();

    //========== P2: u = hidden@Wa + bp ; hv = hidden@Wb (512 tile-tasks) =====
    {
        float (*As)[34] = (float(*)[34])smem;
        float (*Bs)[68] = (float(*)[68])(smem + 544);
        int m0 = (blk >> 3) * 32;
        int n0 = (blk & 7) * 64;
        bool isU = (n0 < NH);
        int tm = tid >> 4, tn = tid & 15;
        int lm = tid >> 2, lk = (tid & 3) * 4;
        int bk = tid >> 4, bn = (tid & 15) * 4;
        float acc[2][4] = {{0.f}};
        for (int k0 = 0; k0 < NH; k0 += 16) {
            if (tid < 128) {
                float4 a4 = *(const float4*)&hidden[(m0 + lm) * NH + k0 + lk];
                As[lk + 0][lm] = a4.x; As[lk + 1][lm] = a4.y;
                As[lk + 2][lm] = a4.z; As[lk + 3][lm] = a4.w;
            }
            int c = k0 + bk;
            float4 b4;
            if (isU) b4 = *(const float4*)&Wp[c * NH + n0 + bn];
            else     b4 = *(const float4*)&Wp[(NH + c) * NH + (n0 - NH) + bn];
            *(float4*)&Bs[bk][bn] = b4;
            __syncthreads();
            #pragma unroll
            for (int kk = 0; kk < 16; kk++) {
                float2 a2 = *(const float2*)&As[kk][tm * 2];
                float4 bv = *(const float4*)&Bs[kk][tn * 4];
                float ar[2] = {a2.x, a2.y};
                float br[4] = {bv.x, bv.y, bv.z, bv.w};
                #pragma unroll
                for (int r = 0; r < 2; r++)
                    #pragma unroll
                    for (int cc = 0; cc < 4; cc++)
                        acc[r][cc] += ar[r] * br[cc];
            }
            __syncthreads();
        }
        if (isU) {
            int col = n0 + tn * 4;
            float4 bb = *(const float4*)&bp[col];
            #pragma unroll
            for (int r = 0; r < 2; r++) {
                int row = m0 + tm * 2 + r;
                float4 o;
                o.x = acc[r][0] + bb.x; o.y = acc[r][1] + bb.y;
                o.z = acc[r][2] + bb.z; o.w = acc[r][3] + bb.w;
                *(float4*)&u[row * NH + col] = o;
            }
        } else {
            int col = (n0 - NH) + tn * 4;
            #pragma unroll
            for (int r = 0; r < 2; r++) {
                int row = m0 + tm * 2 + r;
                float4 o;
                o.x = acc[r][0]; o.y = acc[r][1];
                o.z = acc[r][2]; o.w = acc[r][3];
                *(float4*)&hv[row * NH + col] = o;
            }
        }
    }
    __threadfence();
    grid.sync();

    //========== P3: partial arc scores, 640 tasks grid-strided ==============
    {
        float (*us)[33] = (float(*)[33])smem;            // 2112
        float (*vs)[33] = (float(*)[33])(smem + 2112);   // 2112
        float* wa = smem + 4224;                          // 256 (tot 4480)
        wa[tid] = W_arc[tid];
        int tx = tid & 15, ty = tid >> 4;
        for (int t = blk; t < 640; t += NBLK) {
            int b = t & 15;
            int rest = t >> 4;
            int i0 = (rest & 3) * 32;
            int z = rest >> 2;
            int jt = z % 5, kh = z / 5;
            int j0 = jt * 32;
            int kbase = kh * 128;
            float acc[2][2] = {{0.f}};
            for (int k0 = kbase; k0 < kbase + 128; k0 += 64) {
                #pragma unroll
                for (int h = 0; h < 2; h++) {
                    int idx = tid + h * 256;
                    int row = idx >> 4;
                    int kq  = (idx & 15) * 4;
                    float4 a4 = *(const float4*)&u[(size_t)(b * NL + i0 + row) * NH + k0 + kq];
                    us[kq + 0][row] = a4.x; us[kq + 1][row] = a4.y;
                    us[kq + 2][row] = a4.z; us[kq + 3][row] = a4.w;
                    int j = j0 + row; if (j > 128) j = 128;
                    const float* src = (j == 0) ? (vroot + k0 + kq)
                                     : (hv + (size_t)(b * NL + j - 1) * NH + k0 + kq);
                    float4 b4 = *(const float4*)src;
                    vs[kq + 0][row] = b4.x; vs[kq + 1][row] = b4.y;
                    vs[kq + 2][row] = b4.z; vs[kq + 3][row] = b4.w;
                }
                __syncthreads();
                #pragma unroll 8
                for (int kk = 0; kk < 64; kk++) {
                    float w  = wa[k0 + kk];
                    float u0 = us[kk][ty * 2], u1 = us[kk][ty * 2 + 1];
                    float v0 = vs[kk][tx * 2], v1 = vs[kk][tx * 2 + 1];
                    acc[0][0] += fmaxf(u0 + v0, 0.f) * w;
                    acc[0][1] += fmaxf(u0 + v1, 0.f) * w;
                    acc[1][0] += fmaxf(u1 + v0, 0.f) * w;
                    acc[1][1] += fmaxf(u1 + v1, 0.f) * w;
                }
                __syncthreads();
            }
            float* dst = scores + (size_t)kh * (NM * NJP);
            #pragma unroll
            for (int r = 0; r < 2; r++)
                #pragma unroll
                for (int c = 0; c < 2; c++) {
                    int j = j0 + tx * 2 + c;
                    if (j < NJP)
                        dst[(size_t)(b * NL + i0 + ty * 2 + r) * NJP + j] = acc[r][c];
                }
        }
    }
    __threadfence();
    grid.sync();

    //========== P4: loss, 512 row-group tasks ===============================
    {
        float (*sel_s)[5] = (float(*)[5])smem;            // 1280
        float (*ll_s)[48] = (float(*)[48])(smem + 1280);  // 192
        float* ce_s = smem + 1472;                         // 4
        int*   arc_sh = (int*)(smem + 1476);               // 4
        int r0 = blk * 4;
        int b = r0 >> 7;
        int i_base = r0 & 127;
        int slen = slens[b];
        if (i_base < slen) {
            int w = tid >> 6, lane = tid & 63;
            const float* sc0 = scores;
            const float* sc1 = scores + (size_t)NM * NJP;
            {
                int row = r0 + w;
                const float* p0 = sc0 + (size_t)row * NJP;
                const float* p1 = sc1 + (size_t)row * NJP;
                float x0 = p0[lane] + p1[lane];
                float x1 = p0[lane + 64] + p1[lane + 64];
                bool l0 = (lane == 0);
                float x2 = l0 ? (p0[128] + p1[128]) : -INFINITY;
                float m = fmaxf(fmaxf(x0, x1), x2);
                #pragma unroll
                for (int off = 32; off > 0; off >>= 1)
                    m = fmaxf(m, __shfl_xor(m, off));
                float e = expf(x0 - m) + expf(x1 - m) + (l0 ? expf(x2 - m) : 0.f);
                #pragma unroll
                for (int off = 32; off > 0; off >>= 1)
                    e += __shfl_xor(e, off);
                if (l0) {
                    int a = arcs[row];
                    arc_sh[w] = a;
                    ce_s[w] = (m + logf(e)) - (p0[a] + p1[a]);
                }
            }
            __syncthreads();
            {
                int k = tid;
                #pragma unroll
                for (int r = 0; r < 4; r++) {
                    int a = arc_sh[r];
                    const float* vr = (a == 0) ? vroot
                                    : (hv + (size_t)(b * NL + a - 1) * NH);
                    sel_s[k][r] = fmaxf(u[(size_t)(r0 + r) * NH + k] + vr[k], 0.f);
                }
            }
            __syncthreads();
            if (tid < 180) {
                int r = tid / 45, t = tid - r * 45;
                float lg = b_lab[t];
                #pragma unroll 8
                for (int k = 0; k < NH; k++)
                    lg += sel_s[k][r] * W_lab[k * NTAGS + t];
                ll_s[r][t] = lg;
            } else if (tid < 192) {
                int q = tid - 180;
                ll_s[q / 3][45 + q % 3] = -INFINITY;
            }
            __syncthreads();
            {
                int row = r0 + w;
                float y = (lane < 48) ? ll_s[w][lane] : -INFINITY;
                float m2 = y;
                #pragma unroll
                for (int off = 32; off > 0; off >>= 1)
                    m2 = fmaxf(m2, __shfl_xor(m2, off));
                float e2 = (lane < 48) ? expf(y - m2) : 0.f;
                #pragma unroll
                for (int off = 32; off > 0; off >>= 1)
                    e2 += __shfl_xor(e2, off);
                if (lane == 0) {
                    float lab_ce = (m2 + logf(e2)) - ll_s[w][labels[row]];
                    bool act = (i_base + w) < slen;
                    ce_s[w] = act ? (ce_s[w] + lab_ce) : 0.f;
                }
            }
            __syncthreads();
            if (tid == 0)
                atomicAdd(accum, ce_s[0] + ce_s[1] + ce_s[2] + ce_s[3]);
        }
    }
    grid.sync();

    //========== P5: finalize ================================================
    if (blk == 0 && tid == 0) {
        int d = 0;
        #pragma unroll
        for (int b = 0; b < NB; b++) d += slens[b];
        out[0] = 0.5f * accum[0] / fmaxf((float)d, 1.f);
    }
}

extern "C" void kernel_launch(void* const* d_in, const int* in_sizes, int n_in,
                              void* d_out, int out_size, void* d_ws, size_t ws_size,
                              hipStream_t stream) {
    (void)in_sizes; (void)n_in; (void)out_size; (void)ws_size;
    const float* ctx   = (const float*)d_in[0];
    const int*   slens = (const int*)  d_in[1];
    const int*   arcs  = (const int*)  d_in[2];
    const int*   labs  = (const int*)  d_in[3];
    const float* W1    = (const float*)d_in[4];
    const float* b1    = (const float*)d_in[5];
    const float* root  = (const float*)d_in[6];
    const float* Wp    = (const float*)d_in[7];
    const float* bp    = (const float*)d_in[8];
    const float* W_arc = (const float*)d_in[9];
    const float* W_lab = (const float*)d_in[11];
    const float* b_lab = (const float*)d_in[12];
    float* out = (float*)d_out;

    float* ws     = (float*)d_ws;
    float* hidden = ws + HID_OFF;
    float* u      = ws + U_OFF;
    float* hv     = ws + HV_OFF;
    float* vroot  = ws + VROOT_OFF;
    float* accum  = ws + ACC_OFF;
    float* scores = ws + SC_OFF;

    void* args[] = {
        (void*)&ctx, (void*)&slens, (void*)&arcs, (void*)&labs,
        (void*)&W1, (void*)&b1, (void*)&root, (void*)&Wp, (void*)&bp,
        (void*)&W_arc, (void*)&W_lab, (void*)&b_lab,
        (void*)&hidden, (void*)&u, (void*)&hv, (void*)&vroot,
        (void*)&accum, (void*)&scores, (void*)&out
    };
    hipLaunchCooperativeKernel((void*)fused_all, dim3(NBLK), dim3(256),
                               args, 0, stream);
}

// Round 6
// 223.472 us; speedup vs baseline: 2.3849x; 2.3849x over previous
//
#include <hip/hip_runtime.h>
#include <math.h>

// Problem constants
#define NB 16
#define NL 128
#define DIN 512
#define NH 256
#define NTAGS 45
#define NM (NB*NL)          // 2048 rows
#define NJ (NL+1)           // 129 arc columns
#define NJP 132             // padded score row stride

// ws layout (floats)
#define HID_OFF   0
#define U_OFF     (NM*NH)                 // 524288
#define HV_OFF    (U_OFF + NM*NH)         // 1048576
#define VROOT_OFF (HV_OFF + NM*NH)        // 1572864
#define ACC_OFF   (VROOT_OFF + NH)        // accum(1), done(1), cnt(64)
#define SC_OFF    (ACC_OFF + 68)          // scores: 2 x NM x NJP

// ---------------------------------------------------------------------------
// N1: hidden = relu(ctx@W1+b1). 32x32 tiles, BK=32 -> grid (65,8).
// x==64: y<4 -> vroot quarter; y==4 -> zero accum/done/cnt.
// ---------------------------------------------------------------------------
__global__ __launch_bounds__(256) void gemm_hidden(
    const float* __restrict__ A, const float* __restrict__ W,
    const float* __restrict__ bias, const float* __restrict__ root,
    const float* __restrict__ Wp, float* __restrict__ out,
    float* __restrict__ vroot, int* __restrict__ flags)
{
    __shared__ float As[32][34];
    __shared__ float Bs[32][36];
    int tid = threadIdx.x;

    if (blockIdx.x == 64) {
        int y = blockIdx.y;
        if (y < 4) {                       // vroot cols y*64..y*64+63
            __shared__ float part[256];
            int col = y * 64 + (tid & 63);
            int kc = tid >> 6;
            float p = 0.f;
            #pragma unroll 8
            for (int c = kc * 64; c < kc * 64 + 64; c++)
                p += root[c] * Wp[(NH + c) * NH + col];
            part[kc * 64 + (tid & 63)] = p;
            __syncthreads();
            if (tid < 64)
                vroot[y * 64 + tid] = part[tid] + part[64 + tid]
                                    + part[128 + tid] + part[192 + tid];
        } else if (y == 4) {
            if (tid < 66) flags[tid] = 0;  // accum, done, cnt[64]
        }
        return;
    }

    int m0 = blockIdx.x * 32;
    int n0 = blockIdx.y * 32;
    int lr = tid >> 3, lq = (tid & 7) * 4;    // one float4 per thread
    int tm = tid >> 4, tn = tid & 15;
    float acc[2][2] = {{0.f}};

    for (int k0 = 0; k0 < DIN; k0 += 32) {
        float4 a4 = *(const float4*)&A[(m0 + lr) * DIN + k0 + lq];
        As[lq + 0][lr] = a4.x; As[lq + 1][lr] = a4.y;
        As[lq + 2][lr] = a4.z; As[lq + 3][lr] = a4.w;
        float4 b4 = *(const float4*)&W[(k0 + lr) * NH + n0 + lq];
        *(float4*)&Bs[lr][lq] = b4;
        __syncthreads();
        #pragma unroll
        for (int kk = 0; kk < 32; kk++) {
            float2 a2 = *(const float2*)&As[kk][tm * 2];
            float2 b2 = *(const float2*)&Bs[kk][tn * 2];
            acc[0][0] += a2.x * b2.x; acc[0][1] += a2.x * b2.y;
            acc[1][0] += a2.y * b2.x; acc[1][1] += a2.y * b2.y;
        }
        __syncthreads();
    }
    int col = n0 + tn * 2;
    float2 bb = *(const float2*)&bias[col];
    #pragma unroll
    for (int r = 0; r < 2; r++) {
        int row = m0 + tm * 2 + r;
        float2 o;
        o.x = fmaxf(acc[r][0] + bb.x, 0.f);
        o.y = fmaxf(acc[r][1] + bb.y, 0.f);
        *(float2*)&out[row * NH + col] = o;
    }
}

// ---------------------------------------------------------------------------
// N2: u = hidden@Wa + bp ; hv = hidden@Wb. 32x32 tiles -> grid (64,16).
// ---------------------------------------------------------------------------
__global__ __launch_bounds__(256) void gemm_uv(
    const float* __restrict__ hidden, const float* __restrict__ Wp,
    const float* __restrict__ bp, float* __restrict__ u,
    float* __restrict__ hv)
{
    __shared__ float As[32][34];
    __shared__ float Bs[32][36];
    int tid = threadIdx.x;
    int m0 = blockIdx.x * 32;
    int n0 = blockIdx.y * 32;
    bool isU = (n0 < NH);
    int lr = tid >> 3, lq = (tid & 7) * 4;
    int tm = tid >> 4, tn = tid & 15;
    float acc[2][2] = {{0.f}};

    for (int k0 = 0; k0 < NH; k0 += 32) {
        float4 a4 = *(const float4*)&hidden[(m0 + lr) * NH + k0 + lq];
        As[lq + 0][lr] = a4.x; As[lq + 1][lr] = a4.y;
        As[lq + 2][lr] = a4.z; As[lq + 3][lr] = a4.w;
        int c = k0 + lr;
        float4 b4;
        if (isU) b4 = *(const float4*)&Wp[c * NH + n0 + lq];
        else     b4 = *(const float4*)&Wp[(NH + c) * NH + (n0 - NH) + lq];
        *(float4*)&Bs[lr][lq] = b4;
        __syncthreads();
        #pragma unroll
        for (int kk = 0; kk < 32; kk++) {
            float2 a2 = *(const float2*)&As[kk][tm * 2];
            float2 b2 = *(const float2*)&Bs[kk][tn * 2];
            acc[0][0] += a2.x * b2.x; acc[0][1] += a2.x * b2.y;
            acc[1][0] += a2.y * b2.x; acc[1][1] += a2.y * b2.y;
        }
        __syncthreads();
    }
    if (isU) {
        int col = n0 + tn * 2;
        float2 bb = *(const float2*)&bp[col];
        #pragma unroll
        for (int r = 0; r < 2; r++) {
            int row = m0 + tm * 2 + r;
            float2 o;
            o.x = acc[r][0] + bb.x; o.y = acc[r][1] + bb.y;
            *(float2*)&u[row * NH + col] = o;
        }
    } else {
        int col = (n0 - NH) + tn * 2;
        #pragma unroll
        for (int r = 0; r < 2; r++) {
            int row = m0 + tm * 2 + r;
            float2 o; o.x = acc[r][0]; o.y = acc[r][1];
            *(float2*)&hv[row * NH + col] = o;
        }
    }
}

// ---------------------------------------------------------------------------
// N3: 1152 blocks. Blocks 0..639: arc-score partials (k-split x2), then
// release-increment cnt[b*4+itile]. Blocks 640..1151: loss for 4 rows,
// acquire-spin on cnt (target 10), last-done block finalizes.
// ---------------------------------------------------------------------------
__global__ __launch_bounds__(256) void score_loss(
    const float* __restrict__ u, const float* __restrict__ hv,
    const float* __restrict__ vroot, const float* __restrict__ W_arc,
    const float* __restrict__ W_lab, const float* __restrict__ b_lab,
    const int* __restrict__ slens, const int* __restrict__ arcs,
    const int* __restrict__ labels, int* __restrict__ flags,
    float* __restrict__ scores, float* __restrict__ out)
{
    float* accum = (float*)flags;        // flags[0]
    int* done = flags + 1;               // flags[1]
    int* cnt  = flags + 2;               // flags[2..65]
    int blk = blockIdx.x;
    int tid = threadIdx.x;

    if (blk < 640) {
        //================= producer: one (b, itile, jt, kh) task =============
        __shared__ float us[64][33];
        __shared__ float vs[64][33];
        __shared__ float wa[NH];
        wa[tid] = W_arc[tid];
        int b = blk & 15;
        int rest = blk >> 4;
        int i0 = (rest & 3) * 32;
        int z = rest >> 2;
        int jt = z % 5, kh = z / 5;
        int j0 = jt * 32;
        int kbase = kh * 128;
        int tx = tid & 15, ty = tid >> 4;
        float acc[2][2] = {{0.f}};

        for (int k0 = kbase; k0 < kbase + 128; k0 += 64) {
            #pragma unroll
            for (int h = 0; h < 2; h++) {
                int idx = tid + h * 256;
                int row = idx >> 4;
                int kq  = (idx & 15) * 4;
                float4 a4 = *(const float4*)&u[(size_t)(b * NL + i0 + row) * NH + k0 + kq];
                us[kq + 0][row] = a4.x; us[kq + 1][row] = a4.y;
                us[kq + 2][row] = a4.z; us[kq + 3][row] = a4.w;
                int j = j0 + row; if (j > 128) j = 128;
                const float* src = (j == 0) ? (vroot + k0 + kq)
                                 : (hv + (size_t)(b * NL + j - 1) * NH + k0 + kq);
                float4 b4 = *(const float4*)src;
                vs[kq + 0][row] = b4.x; vs[kq + 1][row] = b4.y;
                vs[kq + 2][row] = b4.z; vs[kq + 3][row] = b4.w;
            }
            __syncthreads();
            #pragma unroll 8
            for (int kk = 0; kk < 64; kk++) {
                float w  = wa[k0 + kk];
                float u0 = us[kk][ty * 2], u1 = us[kk][ty * 2 + 1];
                float v0 = vs[kk][tx * 2], v1 = vs[kk][tx * 2 + 1];
                acc[0][0] += fmaxf(u0 + v0, 0.f) * w;
                acc[0][1] += fmaxf(u0 + v1, 0.f) * w;
                acc[1][0] += fmaxf(u1 + v0, 0.f) * w;
                acc[1][1] += fmaxf(u1 + v1, 0.f) * w;
            }
            __syncthreads();
        }
        float* dst = scores + (size_t)kh * (NM * NJP);
        #pragma unroll
        for (int r = 0; r < 2; r++)
            #pragma unroll
            for (int c = 0; c < 2; c++) {
                int j = j0 + tx * 2 + c;
                if (j < NJP)
                    dst[(size_t)(b * NL + i0 + ty * 2 + r) * NJP + j] = acc[r][c];
            }
        __syncthreads();
        if (tid == 0) {
            __threadfence();                       // release scores
            atomicAdd(&cnt[b * 4 + (i0 >> 5)], 1);
        }
        return;
    }

    //================= consumer: loss for rows r0..r0+3 =====================
    __shared__ float sel_s[NH][5];
    __shared__ float ll_s[4][48];
    __shared__ float ce_s[4];
    __shared__ int   arc_sh[4];
    int c = blk - 640;
    int r0 = c * 4;
    int b = r0 >> 7;
    int i_base = r0 & 127;
    int slen = slens[b];
    bool active = (i_base < slen);

    if (active) {
        if (tid == 0) {
            int idx = b * 4 + (i_base >> 5);
            while (atomicAdd(&cnt[idx], 0) < 10)
                __builtin_amdgcn_s_sleep(8);
        }
        __syncthreads();
        __threadfence();                           // acquire scores

        int w = tid >> 6, lane = tid & 63;
        const float* sc0 = scores;
        const float* sc1 = scores + (size_t)NM * NJP;
        {
            int row = r0 + w;
            const float* p0 = sc0 + (size_t)row * NJP;
            const float* p1 = sc1 + (size_t)row * NJP;
            float x0 = p0[lane] + p1[lane];
            float x1 = p0[lane + 64] + p1[lane + 64];
            bool l0 = (lane == 0);
            float x2 = l0 ? (p0[128] + p1[128]) : -INFINITY;
            float m = fmaxf(fmaxf(x0, x1), x2);
            #pragma unroll
            for (int off = 32; off > 0; off >>= 1)
                m = fmaxf(m, __shfl_xor(m, off));
            float e = expf(x0 - m) + expf(x1 - m) + (l0 ? expf(x2 - m) : 0.f);
            #pragma unroll
            for (int off = 32; off > 0; off >>= 1)
                e += __shfl_xor(e, off);
            if (l0) {
                int a = arcs[row];
                arc_sh[w] = a;
                ce_s[w] = (m + logf(e)) - (p0[a] + p1[a]);
            }
        }
        __syncthreads();
        {
            int k = tid;
            #pragma unroll
            for (int r = 0; r < 4; r++) {
                int a = arc_sh[r];
                const float* vr = (a == 0) ? vroot
                                : (hv + (size_t)(b * NL + a - 1) * NH);
                sel_s[k][r] = fmaxf(u[(size_t)(r0 + r) * NH + k] + vr[k], 0.f);
            }
        }
        __syncthreads();
        if (tid < 180) {
            int r = tid / 45, t = tid - r * 45;
            float lg = b_lab[t];
            #pragma unroll 8
            for (int k = 0; k < NH; k++)
                lg += sel_s[k][r] * W_lab[k * NTAGS + t];
            ll_s[r][t] = lg;
        } else if (tid < 192) {
            int q = tid - 180;
            ll_s[q / 3][45 + q % 3] = -INFINITY;
        }
        __syncthreads();
        {
            int row = r0 + w;
            float y = (lane < 48) ? ll_s[w][lane] : -INFINITY;
            float m2 = y;
            #pragma unroll
            for (int off = 32; off > 0; off >>= 1)
                m2 = fmaxf(m2, __shfl_xor(m2, off));
            float e2 = (lane < 48) ? expf(y - m2) : 0.f;
            #pragma unroll
            for (int off = 32; off > 0; off >>= 1)
                e2 += __shfl_xor(e2, off);
            if (lane == 0) {
                float lab_ce = (m2 + logf(e2)) - ll_s[w][labels[row]];
                bool act = (i_base + w) < slen;
                ce_s[w] = act ? (ce_s[w] + lab_ce) : 0.f;
            }
        }
        __syncthreads();
        if (tid == 0)
            atomicAdd(accum, ce_s[0] + ce_s[1] + ce_s[2] + ce_s[3]);
    }

    // done-count; 512th block finalizes
    if (tid == 0) {
        __threadfence();
        int old = atomicAdd(done, 1);
        if (old == 511) {
            float tot = atomicAdd(accum, 0.f);     // coherent read
            int d = 0;
            #pragma unroll
            for (int bb = 0; bb < NB; bb++) d += slens[bb];
            out[0] = 0.5f * tot / fmaxf((float)d, 1.f);
        }
    }
}

extern "C" void kernel_launch(void* const* d_in, const int* in_sizes, int n_in,
                              void* d_out, int out_size, void* d_ws, size_t ws_size,
                              hipStream_t stream) {
    (void)in_sizes; (void)n_in; (void)out_size; (void)ws_size;
    const float* ctx   = (const float*)d_in[0];
    const int*   slens = (const int*)  d_in[1];
    const int*   arcs  = (const int*)  d_in[2];
    const int*   labs  = (const int*)  d_in[3];
    const float* W1    = (const float*)d_in[4];
    const float* b1    = (const float*)d_in[5];
    const float* root  = (const float*)d_in[6];
    const float* Wp    = (const float*)d_in[7];
    const float* bp    = (const float*)d_in[8];
    const float* W_arc = (const float*)d_in[9];
    const float* W_lab = (const float*)d_in[11];
    const float* b_lab = (const float*)d_in[12];
    float* out = (float*)d_out;

    float* ws     = (float*)d_ws;
    float* hidden = ws + HID_OFF;
    float* u      = ws + U_OFF;
    float* hv     = ws + HV_OFF;
    float* vroot  = ws + VROOT_OFF;
    int*   flags  = (int*)(ws + ACC_OFF);
    float* scores = ws + SC_OFF;

    gemm_hidden<<<dim3(65, 8), 256, 0, stream>>>(ctx, W1, b1, root, Wp,
                                                 hidden, vroot, flags);
    gemm_uv<<<dim3(64, 16), 256, 0, stream>>>(hidden, Wp, bp, u, hv);
    score_loss<<<1152, 256, 0, stream>>>(u, hv, vroot, W_arc, W_lab, b_lab,
                                         slens, arcs, labs, flags, scores, out);
}

// Round 7
// 163.444 us; speedup vs baseline: 3.2608x; 1.3673x over previous
//
#include <hip/hip_runtime.h>
#include <math.h>

// Problem constants
#define NB 16
#define NL 128
#define DIN 512
#define NH 256
#define NTAGS 45
#define NM (NB*NL)          // 2048 rows
#define NJ (NL+1)           // 129 arc columns

// ws layout (floats)
#define HID_OFF   0
#define U_OFF     (NM*NH)                 // 524288
#define HV_OFF    (U_OFF + NM*NH)         // 1048576
#define VROOT_OFF (HV_OFF + NM*NH)        // 1572864
#define ACC_OFF   (VROOT_OFF + NH)        // accum(1), done(1), pad

// ---------------------------------------------------------------------------
// N1: hidden = relu(ctx@W1+b1). 32x32 tiles, BK=32 -> grid (65,8).
// x==64: y<4 -> vroot quarter; y==4 -> zero accum/done.
// ---------------------------------------------------------------------------
__global__ __launch_bounds__(256) void gemm_hidden(
    const float* __restrict__ A, const float* __restrict__ W,
    const float* __restrict__ bias, const float* __restrict__ root,
    const float* __restrict__ Wp, float* __restrict__ out,
    float* __restrict__ vroot, int* __restrict__ flags)
{
    __shared__ float As[32][34];
    __shared__ float Bs[32][36];
    int tid = threadIdx.x;

    if (blockIdx.x == 64) {
        int y = blockIdx.y;
        if (y < 4) {                       // vroot cols y*64..y*64+63
            __shared__ float part[256];
            int col = y * 64 + (tid & 63);
            int kc = tid >> 6;
            float p = 0.f;
            #pragma unroll 8
            for (int c = kc * 64; c < kc * 64 + 64; c++)
                p += root[c] * Wp[(NH + c) * NH + col];
            part[kc * 64 + (tid & 63)] = p;
            __syncthreads();
            if (tid < 64)
                vroot[y * 64 + tid] = part[tid] + part[64 + tid]
                                    + part[128 + tid] + part[192 + tid];
        } else if (y == 4) {
            if (tid < 2) flags[tid] = 0;   // accum, done
        }
        return;
    }

    int m0 = blockIdx.x * 32;
    int n0 = blockIdx.y * 32;
    int lr = tid >> 3, lq = (tid & 7) * 4;
    int tm = tid >> 4, tn = tid & 15;
    float acc[2][2] = {{0.f}};

    for (int k0 = 0; k0 < DIN; k0 += 32) {
        float4 a4 = *(const float4*)&A[(m0 + lr) * DIN + k0 + lq];
        As[lq + 0][lr] = a4.x; As[lq + 1][lr] = a4.y;
        As[lq + 2][lr] = a4.z; As[lq + 3][lr] = a4.w;
        float4 b4 = *(const float4*)&W[(k0 + lr) * NH + n0 + lq];
        *(float4*)&Bs[lr][lq] = b4;
        __syncthreads();
        #pragma unroll
        for (int kk = 0; kk < 32; kk++) {
            float2 a2 = *(const float2*)&As[kk][tm * 2];
            float2 b2 = *(const float2*)&Bs[kk][tn * 2];
            acc[0][0] += a2.x * b2.x; acc[0][1] += a2.x * b2.y;
            acc[1][0] += a2.y * b2.x; acc[1][1] += a2.y * b2.y;
        }
        __syncthreads();
    }
    int col = n0 + tn * 2;
    float2 bb = *(const float2*)&bias[col];
    #pragma unroll
    for (int r = 0; r < 2; r++) {
        int row = m0 + tm * 2 + r;
        float2 o;
        o.x = fmaxf(acc[r][0] + bb.x, 0.f);
        o.y = fmaxf(acc[r][1] + bb.y, 0.f);
        *(float2*)&out[row * NH + col] = o;
    }
}

// ---------------------------------------------------------------------------
// N2: u = hidden@Wa + bp ; hv = hidden@Wb. 32x32 tiles -> grid (64,16).
// ---------------------------------------------------------------------------
__global__ __launch_bounds__(256) void gemm_uv(
    const float* __restrict__ hidden, const float* __restrict__ Wp,
    const float* __restrict__ bp, float* __restrict__ u,
    float* __restrict__ hv)
{
    __shared__ float As[32][34];
    __shared__ float Bs[32][36];
    int tid = threadIdx.x;
    int m0 = blockIdx.x * 32;
    int n0 = blockIdx.y * 32;
    bool isU = (n0 < NH);
    int lr = tid >> 3, lq = (tid & 7) * 4;
    int tm = tid >> 4, tn = tid & 15;
    float acc[2][2] = {{0.f}};

    for (int k0 = 0; k0 < NH; k0 += 32) {
        float4 a4 = *(const float4*)&hidden[(m0 + lr) * NH + k0 + lq];
        As[lq + 0][lr] = a4.x; As[lq + 1][lr] = a4.y;
        As[lq + 2][lr] = a4.z; As[lq + 3][lr] = a4.w;
        int c = k0 + lr;
        float4 b4;
        if (isU) b4 = *(const float4*)&Wp[c * NH + n0 + lq];
        else     b4 = *(const float4*)&Wp[(NH + c) * NH + (n0 - NH) + lq];
        *(float4*)&Bs[lr][lq] = b4;
        __syncthreads();
        #pragma unroll
        for (int kk = 0; kk < 32; kk++) {
            float2 a2 = *(const float2*)&As[kk][tm * 2];
            float2 b2 = *(const float2*)&Bs[kk][tn * 2];
            acc[0][0] += a2.x * b2.x; acc[0][1] += a2.x * b2.y;
            acc[1][0] += a2.y * b2.x; acc[1][1] += a2.y * b2.y;
        }
        __syncthreads();
    }
    if (isU) {
        int col = n0 + tn * 2;
        float2 bb = *(const float2*)&bp[col];
        #pragma unroll
        for (int r = 0; r < 2; r++) {
            int row = m0 + tm * 2 + r;
            float2 o;
            o.x = acc[r][0] + bb.x; o.y = acc[r][1] + bb.y;
            *(float2*)&u[row * NH + col] = o;
        }
    } else {
        int col = (n0 - NH) + tn * 2;
        #pragma unroll
        for (int r = 0; r < 2; r++) {
            int row = m0 + tm * 2 + r;
            float2 o; o.x = acc[r][0]; o.y = acc[r][1];
            *(float2*)&hv[row * NH + col] = o;
        }
    }
}

// ---------------------------------------------------------------------------
// N3: fused scores+loss. 512 blocks, 4 rows each; wave = row.
// Arc scores kept in registers (a0: j=lane, a1: j=lane+64, a2: j=128);
// v staged k-major in LDS (stride 133 -> conflict-free). Wave-level softmax.
// Label head as in R4. Last-done block finalizes.
// ---------------------------------------------------------------------------
__global__ __launch_bounds__(256) void fused_score_loss(
    const float* __restrict__ u, const float* __restrict__ hv,
    const float* __restrict__ vroot, const float* __restrict__ W_arc,
    const float* __restrict__ W_lab, const float* __restrict__ b_lab,
    const int* __restrict__ slens, const int* __restrict__ arcs,
    const int* __restrict__ labels, int* __restrict__ flags,
    float* __restrict__ out)
{
    float* accum = (float*)flags;
    int* done = flags + 1;
    __shared__ float vs[64][133];     // k-major v chunk (34048 B)
    __shared__ float u_s[64][5];      // k-major u rows (1280 B)
    __shared__ float wa[NH];
    __shared__ float sel_s[NH][5];
    __shared__ float ll_s[4][48];
    __shared__ float ce_s[4];
    __shared__ int   arc_sh[4];

    int blk = blockIdx.x;
    int tid = threadIdx.x;
    int r0 = blk * 4;
    int b = r0 >> 7;
    int i_base = r0 & 127;
    int slen = slens[b];
    bool active = (i_base < slen);    // block-uniform

    if (active) {
        wa[tid] = W_arc[tid];
        int i  = tid >> 6;            // wave id = row in group
        int jl = tid & 63;
        float a0 = 0.f, a1 = 0.f, a2 = 0.f;

        for (int k0 = 0; k0 < NH; k0 += 64) {
            if (tid < 64) {           // stage u: 4 rows x 64 k
                int ir = tid >> 4, q = tid & 15;
                float4 a4 = *(const float4*)&u[(size_t)(r0 + ir) * NH + k0 + q * 4];
                u_s[q * 4 + 0][ir] = a4.x; u_s[q * 4 + 1][ir] = a4.y;
                u_s[q * 4 + 2][ir] = a4.z; u_s[q * 4 + 3][ir] = a4.w;
            }
            #pragma unroll               // stage v rows 1..128 (from hv)
            for (int h = 0; h < 8; h++) {
                int idx = h * 256 + tid;
                int jr = idx >> 4;       // 0..127 -> col jr+1
                int q  = idx & 15;
                float4 b4 = *(const float4*)&hv[(size_t)(b * NL + jr) * NH + k0 + q * 4];
                vs[q * 4 + 0][jr + 1] = b4.x; vs[q * 4 + 1][jr + 1] = b4.y;
                vs[q * 4 + 2][jr + 1] = b4.z; vs[q * 4 + 3][jr + 1] = b4.w;
            }
            if (tid < 16) {              // stage v col 0 (root)
                float4 b4 = *(const float4*)&vroot[k0 + tid * 4];
                vs[tid * 4 + 0][0] = b4.x; vs[tid * 4 + 1][0] = b4.y;
                vs[tid * 4 + 2][0] = b4.z; vs[tid * 4 + 3][0] = b4.w;
            }
            __syncthreads();
            #pragma unroll 8
            for (int kk = 0; kk < 64; kk++) {
                float uv = u_s[kk][i];           // wave-uniform
                float w  = wa[k0 + kk];
                a0 += fmaxf(uv + vs[kk][jl     ], 0.f) * w;
                a1 += fmaxf(uv + vs[kk][jl + 64], 0.f) * w;
                a2 += fmaxf(uv + vs[kk][128    ], 0.f) * w;   // uniform
            }
            __syncthreads();
        }

        // ---- wave-level arc softmax CE (129 cols in registers) ----
        int row = r0 + i;
        float m = fmaxf(fmaxf(a0, a1), a2);      // a2 idempotent under max
        #pragma unroll
        for (int off = 32; off > 0; off >>= 1)
            m = fmaxf(m, __shfl_xor(m, off));
        float e = expf(a0 - m) + expf(a1 - m) + ((jl == 0) ? expf(a2 - m) : 0.f);
        #pragma unroll
        for (int off = 32; off > 0; off >>= 1)
            e += __shfl_xor(e, off);
        int a = arcs[row];                       // wave-uniform
        float s_arc = (a < 64) ? __shfl(a0, a)
                    : (a < 128) ? __shfl(a1, a - 64) : a2;
        if (jl == 0) {
            arc_sh[i] = a;
            ce_s[i] = (m + logf(e)) - s_arc;
        }
        __syncthreads();

        // ---- sel = relu(u_row + v[arc]), staged stride-5 ----
        #pragma unroll
        for (int r = 0; r < 4; r++) {
            int ar = arc_sh[r];
            const float* vr = (ar == 0) ? vroot
                            : (hv + (size_t)(b * NL + ar - 1) * NH);
            sel_s[tid][r] = fmaxf(u[(size_t)(r0 + r) * NH + tid] + vr[tid], 0.f);
        }
        __syncthreads();

        // ---- label logits: threads 0..179 -> (row, tag) ----
        if (tid < 180) {
            int r = tid / 45, t = tid - r * 45;
            float lg = b_lab[t];
            #pragma unroll 8
            for (int k = 0; k < NH; k++)
                lg += sel_s[k][r] * W_lab[k * NTAGS + t];
            ll_s[r][t] = lg;
        } else if (tid < 192) {
            int q = tid - 180;
            ll_s[q / 3][45 + q % 3] = -INFINITY;
        }
        __syncthreads();

        // ---- label softmax CE + mask + combine ----
        {
            float y = (jl < 48) ? ll_s[i][jl] : -INFINITY;
            float m2 = y;
            #pragma unroll
            for (int off = 32; off > 0; off >>= 1)
                m2 = fmaxf(m2, __shfl_xor(m2, off));
            float e2 = (jl < 48) ? expf(y - m2) : 0.f;
            #pragma unroll
            for (int off = 32; off > 0; off >>= 1)
                e2 += __shfl_xor(e2, off);
            if (jl == 0) {
                float lab_ce = (m2 + logf(e2)) - ll_s[i][labels[row]];
                bool act = (i_base + i) < slen;
                ce_s[i] = act ? (ce_s[i] + lab_ce) : 0.f;
            }
        }
        __syncthreads();
        if (tid == 0)
            atomicAdd(accum, ce_s[0] + ce_s[1] + ce_s[2] + ce_s[3]);
    }

    // ---- done counter; 512th block finalizes ----
    if (tid == 0) {
        __threadfence();
        int old = atomicAdd(done, 1);
        if (old == 511) {
            float tot = atomicAdd(accum, 0.f);   // coherent read
            int d = 0;
            #pragma unroll
            for (int bb = 0; bb < NB; bb++) d += slens[bb];
            out[0] = 0.5f * tot / fmaxf((float)d, 1.f);
        }
    }
}

extern "C" void kernel_launch(void* const* d_in, const int* in_sizes, int n_in,
                              void* d_out, int out_size, void* d_ws, size_t ws_size,
                              hipStream_t stream) {
    (void)in_sizes; (void)n_in; (void)out_size; (void)ws_size;
    const float* ctx   = (const float*)d_in[0];
    const int*   slens = (const int*)  d_in[1];
    const int*   arcs  = (const int*)  d_in[2];
    const int*   labs  = (const int*)  d_in[3];
    const float* W1    = (const float*)d_in[4];
    const float* b1    = (const float*)d_in[5];
    const float* root  = (const float*)d_in[6];
    const float* Wp    = (const float*)d_in[7];
    const float* bp    = (const float*)d_in[8];
    const float* W_arc = (const float*)d_in[9];
    const float* W_lab = (const float*)d_in[11];
    const float* b_lab = (const float*)d_in[12];
    float* out = (float*)d_out;

    float* ws     = (float*)d_ws;
    float* hidden = ws + HID_OFF;
    float* u      = ws + U_OFF;
    float* hv     = ws + HV_OFF;
    float* vroot  = ws + VROOT_OFF;
    int*   flags  = (int*)(ws + ACC_OFF);

    gemm_hidden<<<dim3(65, 8), 256, 0, stream>>>(ctx, W1, b1, root, Wp,
                                                 hidden, vroot, flags);
    gemm_uv<<<dim3(64, 16), 256, 0, stream>>>(hidden, Wp, bp, u, hv);
    fused_score_loss<<<512, 256, 0, stream>>>(u, hv, vroot, W_arc, W_lab, b_lab,
                                              slens, arcs, labs, flags, out);
}